// Round 2
// baseline (4916.114 us; speedup 1.0000x reference)
//
#include <hip/hip_runtime.h>
#include <hip/hip_bf16.h>

// SparseBottleneck, output-stationary rewrite.
// Old kernel was at 99% of the global-atomic op ceiling (345.6M fp32 atomics
// per sconv = 304.8 G/s ~= 1/TCC-channel/cycle). New design: bin contributions
// by (output_tile, k) once (maps shared by conv1/conv3), then one block per
// 128-row output tile accumulates in an LDS fp32 tile via ds_add_f32 and
// writes each output row exactly once.

typedef __attribute__((ext_vector_type(8))) short short8;
typedef __attribute__((ext_vector_type(4))) float f32x4;

#define CDIM 128
#define BM   128
#define KTAPS 27
#define NEG_SLOPE 0.2f

__device__ __forceinline__ unsigned short f2bf(float x) {
    union { float f; unsigned u; } un; un.f = x;
    unsigned r = un.u + 0x7fffu + ((un.u >> 16) & 1u);   // RNE
    return (unsigned short)(r >> 16);
}

__device__ __forceinline__ float lrelu(float x) {
    return x >= 0.f ? x : NEG_SLOPE * x;
}

// swizzled LDS index for conv2's staging (proven in previous kernel)
__device__ __forceinline__ int swz(int r, int c) {
    return (r << 7) + ((((c >> 3) ^ (r & 15)) << 3));
}

// ---------------------------------------------------------------- converters
__global__ void cvt_feats_kernel(const float* __restrict__ in,
                                 unsigned short* __restrict__ out, int n4) {
    int i = blockIdx.x * blockDim.x + threadIdx.x;
    if (i >= n4) return;
    float4 v = reinterpret_cast<const float4*>(in)[i];
    ushort4 o;
    o.x = f2bf(v.x); o.y = f2bf(v.y); o.z = f2bf(v.z); o.w = f2bf(v.w);
    reinterpret_cast<ushort4*>(out)[i] = o;
}

// W1/W3: [K][Cin][Cout] -> Wt[K][Cout][Cin] bf16 ; W2: [Cin][Cout] -> W2t[Cout][Cin]
__global__ void cvt_weights_kernel(const float* __restrict__ W1,
                                   const float* __restrict__ W2,
                                   const float* __restrict__ W3,
                                   unsigned short* __restrict__ W1t,
                                   unsigned short* __restrict__ W2t,
                                   unsigned short* __restrict__ W3t) {
    const int KW = KTAPS * 128 * 128;                 // 442368
    int t = blockIdx.x * blockDim.x + threadIdx.x;
    if (t < KW) {
        int k = t >> 14, r = t & 16383, n = r >> 7, kk = r & 127;
        W1t[t] = f2bf(W1[(k << 14) + (kk << 7) + n]);
    } else if (t < 2 * KW) {
        int t2 = t - KW;
        int k = t2 >> 14, r = t2 & 16383, n = r >> 7, kk = r & 127;
        W3t[t2] = f2bf(W3[(k << 14) + (kk << 7) + n]);
    } else if (t < 2 * KW + 16384) {
        int t2 = t - 2 * KW;
        int n = t2 >> 7, kk = t2 & 127;
        W2t[t2] = f2bf(W2[(kk << 7) + n]);
    }
}

// ---------------------------------------------------------------- binning prep
// bin = (out_row >> 7) * 27 + k ; runs once, reused by conv1 AND conv3.
__global__ void hist_kernel(const int* __restrict__ out_map,
                            int* __restrict__ cnt, int M) {
    int m = blockIdx.x * 256 + threadIdx.x;
    if (m >= M) return;
    int k = blockIdx.y;
    int orow = out_map[(size_t)k * M + m];
    atomicAdd(cnt + ((orow >> 7) * KTAPS + k), 1);
}

// chunk counts = ceil(cnt/16); exclusive scan (3 tiny kernels)
__global__ void scan_a_kernel(const int* __restrict__ cnt, int* __restrict__ cs,
                              int* __restrict__ partials, int NB) {
    __shared__ int sd[256];
    int tid = threadIdx.x, bin = blockIdx.x * 256 + tid;
    int v = (bin < NB) ? ((cnt[bin] + 15) >> 4) : 0;
    sd[tid] = v; __syncthreads();
    for (int off = 1; off < 256; off <<= 1) {
        int t = (tid >= off) ? sd[tid - off] : 0; __syncthreads();
        sd[tid] += t; __syncthreads();
    }
    if (bin < NB) cs[bin] = sd[tid] - v;      // block-local exclusive
    if (tid == 255) partials[blockIdx.x] = sd[255];
}

__global__ void scan_b_kernel(int* __restrict__ partials, int NBb) {
    __shared__ int sd[256];
    int tid = threadIdx.x;
    int v = (tid < NBb) ? partials[tid] : 0;
    sd[tid] = v; __syncthreads();
    for (int off = 1; off < 256; off <<= 1) {
        int t = (tid >= off) ? sd[tid - off] : 0; __syncthreads();
        sd[tid] += t; __syncthreads();
    }
    partials[tid] = sd[tid] - v;              // exclusive; partials[NBb] = total
}

__global__ void scan_c_kernel(int* __restrict__ cs, const int* __restrict__ partials,
                              int NB, int NBb) {
    int bin = blockIdx.x * 256 + threadIdx.x;
    if (bin < NB) cs[bin] += partials[blockIdx.x];
    if (bin == 0) cs[NB] = partials[NBb];
}

__global__ void fill_kernel(int* __restrict__ p, int n, int v) {
    int i = blockIdx.x * 256 + threadIdx.x;
    if (i < n) p[i] = v;
}

// entry pack: (k<<26) | (in_row<<8) | (out_row & 127)   -- 31 bits
__global__ void scatter_kernel(const int* __restrict__ in_map,
                               const int* __restrict__ out_map,
                               const int* __restrict__ cs,
                               int* __restrict__ cursor,
                               int* __restrict__ pairs, int M) {
    int m = blockIdx.x * 256 + threadIdx.x;
    if (m >= M) return;
    int k = blockIdx.y;
    size_t e = (size_t)k * M + m;
    int orow = out_map[e], irow = in_map[e];
    int bin = (orow >> 7) * KTAPS + k;
    int pos = atomicAdd(cursor + bin, 1);
    pairs[(size_t)cs[bin] * 16 + pos] = (k << 26) | (irow << 8) | (orow & 127);
}

// ---------------------------------------------------------------- fused sconv
// One block per 128-row output tile. LDS fp32 acc tile; ds_add_f32 scatter.
// Chunks of 16 contributions, uniform k per chunk (bins are 16-padded with
// dummies: in_row=N -> zero feats row, scat_row=0 -> adds exact 0.0f).
// MODE 0: conv1 -> bf16 lrelu(acc) to bf_out.  MODE 1: conv3 -> acc*mask fp32.
template<int MODE>
__global__ __launch_bounds__(512, 4)
void conv_fused_kernel(const unsigned short* __restrict__ A,    // [N+1,128] bf16, row N = 0
                       const unsigned short* __restrict__ Wt,   // [27,128,128] bf16 [k][n][kk]
                       const int* __restrict__ pairs,
                       const int* __restrict__ cs,              // [NB+1] chunk starts
                       unsigned short* __restrict__ bf_out,     // MODE 0
                       float* __restrict__ f_out,               // MODE 1
                       const float* __restrict__ mask,
                       int N) {
    __shared__ float lacc[128 * 128];                            // 64 KB -> 2 blocks/CU
    const int tid  = threadIdx.x;
    const int tile = blockIdx.x;

    #pragma unroll
    for (int i = tid; i < 128 * 128 / 4; i += 512)
        reinterpret_cast<f32x4*>(lacc)[i] = (f32x4){0.f, 0.f, 0.f, 0.f};
    __syncthreads();

    const int lo = cs[tile * KTAPS], hi = cs[tile * KTAPS + KTAPS];
    const int wid = tid >> 6, lane = tid & 63;
    const int lrow = lane & 15, quad = lane >> 4;

    // contiguous span per wave: consecutive chunks share k -> W_k hits L1
    const int total = hi - lo;
    const int per   = (total + 7) >> 3;
    const int c0 = lo + wid * per;
    const int c1 = (c0 + per < hi) ? (c0 + per) : hi;

    for (int c = c0; c < c1; ++c) {
        int pk   = pairs[c * 16 + lrow];           // entry lrow of this chunk
        int irow = (pk >> 8) & 0x3FFFF;
        int srow = pk & 0x7F;
        int k    = ((unsigned)__shfl(pk, 0)) >> 26;  // entry 0 is always real

        const unsigned short* wk = Wt + ((size_t)k << 14);
        const unsigned short* ar = A + (size_t)irow * CDIM + quad * 8;
        short8 a0 = *reinterpret_cast<const short8*>(ar);
        short8 a1 = *reinterpret_cast<const short8*>(ar + 32);
        short8 a2 = *reinterpret_cast<const short8*>(ar + 64);
        short8 a3 = *reinterpret_cast<const short8*>(ar + 96);

        int sr0 = __shfl(srow, quad * 4 + 0);
        int sr1 = __shfl(srow, quad * 4 + 1);
        int sr2 = __shfl(srow, quad * 4 + 2);
        int sr3 = __shfl(srow, quad * 4 + 3);

        #pragma unroll 2
        for (int j = 0; j < 8; ++j) {
            const unsigned short* wb = wk + ((j * 16 + lrow) << 7) + quad * 8;
            f32x4 acc = {0.f, 0.f, 0.f, 0.f};
            acc = __builtin_amdgcn_mfma_f32_16x16x32_bf16(a0, *reinterpret_cast<const short8*>(wb),      acc, 0, 0, 0);
            acc = __builtin_amdgcn_mfma_f32_16x16x32_bf16(a1, *reinterpret_cast<const short8*>(wb + 32), acc, 0, 0, 0);
            acc = __builtin_amdgcn_mfma_f32_16x16x32_bf16(a2, *reinterpret_cast<const short8*>(wb + 64), acc, 0, 0, 0);
            acc = __builtin_amdgcn_mfma_f32_16x16x32_bf16(a3, *reinterpret_cast<const short8*>(wb + 96), acc, 0, 0, 0);
            // C/D: col = lane&15 (within 16-col tile j), row = quad*4+reg
            float* colp = lacc + j * 16 + lrow;
            atomicAdd(colp + (sr0 << 7), acc[0]);
            atomicAdd(colp + (sr1 << 7), acc[1]);
            atomicAdd(colp + (sr2 << 7), acc[2]);
            atomicAdd(colp + (sr3 << 7), acc[3]);
        }
    }
    __syncthreads();

    // epilogue: each output row written exactly once, coalesced
    const int gbase = tile << 7;
    #pragma unroll
    for (int it = 0; it < 8; ++it) {
        int flat = it * 512 + tid;                 // 4096 = 128 rows * 32 f4
        int r = flat >> 5, c4 = flat & 31;
        int g = gbase + r;
        if (g < N) {
            f32x4 v = *reinterpret_cast<f32x4*>(&lacc[r * CDIM + c4 * 4]);
            if (MODE == 0) {
                ushort4 o;
                o.x = f2bf(lrelu(v[0])); o.y = f2bf(lrelu(v[1]));
                o.z = f2bf(lrelu(v[2])); o.w = f2bf(lrelu(v[3]));
                *reinterpret_cast<ushort4*>(bf_out + (size_t)g * CDIM + c4 * 4) = o;
            } else {
                float mv = mask[g];
                f32x4 o = {v[0] * mv, v[1] * mv, v[2] * mv, v[3] * mv};
                *reinterpret_cast<f32x4*>(f_out + (size_t)g * CDIM + c4 * 4) = o;
            }
        }
    }
}

// ---------------------------------------------------------------- dense conv2
// c2 = bf16(lrelu( c1 @ W2 ))  -- c1 already lrelu'd bf16 (written by conv1)
__global__ __launch_bounds__(256, 2)
void conv2_kernel(const unsigned short* __restrict__ c1,      // [N,128] bf16
                  const unsigned short* __restrict__ W2t,     // [128,128] bf16 [n][kk]
                  unsigned short* __restrict__ c2,            // [N,128] bf16
                  int N) {
    const int mbase = blockIdx.x * BM;
    const int tid   = threadIdx.x;

    __shared__ unsigned short lA[BM * CDIM];
    __shared__ unsigned short lW[CDIM * CDIM];

    #pragma unroll
    for (int i = 0; i < 8; ++i) {
        int flat = (i * 256 + tid) * 8;
        int row = flat >> 7, col = flat & 127;
        short8 v = *reinterpret_cast<const short8*>(W2t + flat);
        *reinterpret_cast<short8*>(&lW[swz(row, col)]) = v;
    }

    #pragma unroll
    for (int p = 0; p < 8; ++p) {
        int r = p * 16 + (tid >> 4);
        int c = (tid & 15) * 8;
        int m = mbase + r;
        short8 v = {0, 0, 0, 0, 0, 0, 0, 0};
        if (m < N) v = *reinterpret_cast<const short8*>(c1 + (size_t)m * CDIM + c);
        *reinterpret_cast<short8*>(&lA[swz(r, c)]) = v;
    }
    __syncthreads();

    const int wid  = tid >> 6, lane = tid & 63;
    const int wr   = (wid >> 1) * 64, wc = (wid & 1) * 64;
    const int lrow = lane & 15, quad = lane >> 4;

    f32x4 acc[4][4];
    #pragma unroll
    for (int i = 0; i < 4; ++i)
        #pragma unroll
        for (int j = 0; j < 4; ++j)
            acc[i][j] = {0.f, 0.f, 0.f, 0.f};

    #pragma unroll
    for (int s = 0; s < 4; ++s) {
        const int kf = s * 32 + quad * 8;
        short8 a[4], b[4];
        #pragma unroll
        for (int i = 0; i < 4; ++i)
            a[i] = *reinterpret_cast<const short8*>(&lA[swz(wr + i * 16 + lrow, kf)]);
        #pragma unroll
        for (int j = 0; j < 4; ++j)
            b[j] = *reinterpret_cast<const short8*>(&lW[swz(wc + j * 16 + lrow, kf)]);
        #pragma unroll
        for (int i = 0; i < 4; ++i)
            #pragma unroll
            for (int j = 0; j < 4; ++j)
                acc[i][j] = __builtin_amdgcn_mfma_f32_16x16x32_bf16(a[i], b[j], acc[i][j], 0, 0, 0);
    }

    #pragma unroll
    for (int i = 0; i < 4; ++i) {
        #pragma unroll
        for (int reg = 0; reg < 4; ++reg) {
            int m = mbase + wr + i * 16 + quad * 4 + reg;
            if (m < N) {
                unsigned short* dst = c2 + (size_t)m * CDIM + wc + lrow;
                #pragma unroll
                for (int j = 0; j < 4; ++j)
                    dst[j * 16] = f2bf(lrelu(acc[i][j][reg]));
            }
        }
    }
}

// ---------------------------------------------------------------- launch
extern "C" void kernel_launch(void* const* d_in, const int* in_sizes, int n_in,
                              void* d_out, int out_size, void* d_ws, size_t ws_size,
                              hipStream_t stream) {
    const float* feats   = (const float*)d_in[0];
    const float* W1      = (const float*)d_in[1];
    const float* W2      = (const float*)d_in[2];
    const float* W3      = (const float*)d_in[3];
    const int*   in_map  = (const int*)d_in[4];
    const int*   out_map = (const int*)d_in[5];
    const float* mask    = (const float*)d_in[6];
    float*       out     = (float*)d_out;

    const int K   = KTAPS;
    const int N   = in_sizes[0] / CDIM;           // 200000
    const int M   = in_sizes[4] / K;              // 100000
    const int NT  = (N + 127) >> 7;               // 1563 output tiles
    const int NB  = NT * K;                       // 42201 bins
    const int NBb = (NB + 255) >> 8;              // 165 scan blocks (<=256 req)
    const int CAP = K * M + 16 * NB;              // padded entry capacity

    // workspace layout (512B-aligned sub-buffers)
    char* w = (char*)d_ws;
    size_t o = 0;
    auto alloc = [&](size_t bytes) -> void* {
        void* p = w + o; o = (o + bytes + 511) & ~(size_t)511; return p;
    };
    unsigned short* Abf  = (unsigned short*)alloc((size_t)(N + 1) * CDIM * 2); // feats bf16; reused as c2
    unsigned short* W1t  = (unsigned short*)alloc((size_t)K * CDIM * CDIM * 2);
    unsigned short* W3t  = (unsigned short*)alloc((size_t)K * CDIM * CDIM * 2);
    unsigned short* W2t  = (unsigned short*)alloc((size_t)CDIM * CDIM * 2);
    int* cnt      = (int*)alloc((size_t)NB * 4);
    int* cursor   = (int*)alloc((size_t)NB * 4);
    int* cs       = (int*)alloc((size_t)(NB + 1) * 4);
    int* partials = (int*)alloc(256 * 4);
    int* pairs    = (int*)alloc((size_t)CAP * 4);
    if (o > ws_size) return;   // fail loudly rather than corrupt

    unsigned short* c1bf = (unsigned short*)d_out;   // c1 (bf16, lrelu'd) lives in d_out

    // convert inputs
    const int n4 = N * CDIM / 4;
    cvt_feats_kernel<<<(n4 + 255) / 256, 256, 0, stream>>>(feats, Abf, n4);
    hipMemsetAsync(Abf + (size_t)N * CDIM, 0, CDIM * 2, stream);  // zero row N (dummy target)
    const int wtot = 2 * K * CDIM * CDIM + CDIM * CDIM;
    cvt_weights_kernel<<<(wtot + 255) / 256, 256, 0, stream>>>(W1, W2, W3, W1t, W2t, W3t);

    // binning prep (shared by conv1 & conv3)
    hipMemsetAsync(cnt, 0, (size_t)NB * 4, stream);
    hipMemsetAsync(cursor, 0, (size_t)NB * 4, stream);
    dim3 gmap((M + 255) / 256, K);
    hist_kernel<<<gmap, 256, 0, stream>>>(out_map, cnt, M);
    scan_a_kernel<<<NBb, 256, 0, stream>>>(cnt, cs, partials, NB);
    scan_b_kernel<<<1, 256, 0, stream>>>(partials, NBb);
    scan_c_kernel<<<NBb, 256, 0, stream>>>(cs, partials, NB, NBb);
    const int DUMMY = (N << 8);                   // in_row=N (zero row), scat_row=0, k=0
    fill_kernel<<<(CAP + 255) / 256, 256, 0, stream>>>(pairs, CAP, DUMMY);
    scatter_kernel<<<gmap, 256, 0, stream>>>(in_map, out_map, cs, cursor, pairs, M);

    // conv1: feats -> c1 (bf16, lrelu'd, in d_out)
    conv_fused_kernel<0><<<NT, 512, 0, stream>>>(Abf, W1t, pairs, cs, c1bf, nullptr, nullptr, N);
    // conv2: c1 @ W2 -> c2 (bf16, overwrites Abf; row N stays zero)
    conv2_kernel<<<NT, 256, 0, stream>>>(c1bf, W2t, Abf, N);
    // conv3: c2 -> out (fp32, *mask fused; overwrites c1 region after conv2 read it)
    conv_fused_kernel<1><<<NT, 512, 0, stream>>>(Abf, W3t, pairs, cs, nullptr, out, mask, N);
}